// Round 6
// baseline (417.613 us; speedup 1.0000x reference)
//
#include <hip/hip_runtime.h>
#include <math.h>

typedef __attribute__((ext_vector_type(8))) short short8;
typedef __attribute__((ext_vector_type(4))) float f32x4;

#define G_ 1000
#define N_ 256
#define E_ 1024
#define F_ 128
#define D1_ 128
#define D2_ 64
#define K1_ 32
#define K2_ 8
#define MD_ 128
#define LB_ 10
#define ME_ 16000

// ---- workspace float offsets (regions verified non-overlapping)
#define OFS_PEN    0
#define OFS_EMB    16                    // float[1000*512]            -> 512016
#define OFS_XW1M   512016                // float[1000*128]            -> 640016
#define OFS_XW2M   640016                // float[1000*10]             -> 650016
#define OFS_DINVM  650016                // float[1000]                -> 651016
#define OFS_WNORM  651016                // float[16000]               -> 667016
#define OFS_ROWSTM 667016                // int[1001]                  -> 668017
#define OFS_WSRC   668032                // u16[16000] = 8000 floats   -> 676032
#define OFS_WFRAG  676032                // u16[28672]: w1f 16384 | w2f 8192 | wf1hi 2048 | wf1lo 2048

static __device__ __forceinline__ unsigned short f2bf(float f) {
  unsigned u = __builtin_bit_cast(unsigned, f);
  u += 0x7fff + ((u >> 16) & 1);          // RNE
  return (unsigned short)(u >> 16);
}
static __device__ __forceinline__ float bf2f(unsigned short h) {
  return __builtin_bit_cast(float, (unsigned)h << 16);
}

// Pack weights into bf16 MFMA B-fragment layout; zero the penalty accumulator.
// B frag (16x16x32): lane l holds B[k = ks*32 + (l>>4)*8 + j][col = nt*16 + (l&15)], j=0..7
__global__ __launch_bounds__(256)
void prep_kernel(const float* __restrict__ W1, const float* __restrict__ W2,
                 const float* __restrict__ Wf1,
                 unsigned short* __restrict__ frag, float* __restrict__ ws) {
  int t = blockIdx.x * 256 + threadIdx.x;
  if (t == 0) ws[OFS_PEN] = 0.f;
  unsigned short* w1f  = frag;
  unsigned short* w2f  = frag + 16384;
  unsigned short* wf1h = frag + 24576;
  unsigned short* wf1l = frag + 26624;
  for (int idx = t; idx < 16384; idx += gridDim.x * 256) {
    int j = idx & 7, l = (idx >> 3) & 63, ks = (idx >> 9) & 3, nt = idx >> 11;
    w1f[idx] = f2bf(W1[(ks * 32 + (l >> 4) * 8 + j) * D1_ + nt * 16 + (l & 15)]);
  }
  for (int idx = t; idx < 8192; idx += gridDim.x * 256) {
    int j = idx & 7, l = (idx >> 3) & 63, ks = (idx >> 9) & 3, nt = idx >> 11;
    w2f[idx] = f2bf(W2[(ks * 32 + (l >> 4) * 8 + j) * D2_ + nt * 16 + (l & 15)]);
  }
  for (int idx = t; idx < 2048; idx += gridDim.x * 256) {
    int j = idx & 7, l = (idx >> 3) & 63, ks = (idx >> 9) & 1, nt = idx >> 10;
    float v = Wf1[(ks * 32 + (l >> 4) * 8 + j) * K1_ + nt * 16 + (l & 15)];
    unsigned short hi = f2bf(v);
    wf1h[idx] = hi;
    wf1l[idx] = f2bf(v - bf2f(hi));
  }
}

// One block (512 threads = 8 waves) per graph.
__global__ __launch_bounds__(512, 4)
void graph_kernel(const float* __restrict__ X, const int* __restrict__ GE,
                  const unsigned short* __restrict__ FR,
                  const float* __restrict__ b1, const float* __restrict__ b2,
                  const float* __restrict__ bf1, const float* __restrict__ bf2,
                  const float* __restrict__ Wf2,
                  float* __restrict__ ws)
{
  const unsigned short* W1F  = FR;
  const unsigned short* W2F  = FR + 16384;
  const unsigned short* Wf1H = FR + 24576;
  const unsigned short* Wf1L = FR + 26624;

  extern __shared__ unsigned char smemraw[];
  // R1 (33792 B): conv phase = chunkA [256][40] u16; post-conv = h2T [64][264] u16
  unsigned short* chunkA = (unsigned short*)smemraw;
  unsigned short* h2T    = (unsigned short*)smemraw;
  // R2 (36864 B): h2s [256][72] u16; overlay a_stf f32[256][34] (attention)
  unsigned short* h2s  = (unsigned short*)(smemraw + 33792);
  float*          a_stf = (float*)(smemraw + 33792);
  // R3: enorm f32[1024] | esrc u16[1024] | rowst | fill | dinv | red
  //     overlay after conv: att_hi u16[8][264] @70656, att_lo @74880 (ends 79104; red untouched)
  float*          enorm  = (float*)(smemraw + 70656);
  unsigned short* att_hi = (unsigned short*)(smemraw + 70656);
  unsigned short* att_lo = (unsigned short*)(smemraw + 74880);
  unsigned short* esrc   = (unsigned short*)(smemraw + 74752);
  int*            rowst  = (int*)(smemraw + 76800);
  int*            fill   = (int*)(smemraw + 77824);
  float*          dinv_s = (float*)(smemraw + 78848);
  float*          red    = (float*)(smemraw + 79872);   // f32[256]

  const int g = blockIdx.x, tid = threadIdx.x;
  const int w = tid >> 6, lane = tid & 63;
  const int l15 = lane & 15, l4 = lane >> 4;
  const float* xg = X + (size_t)g * (N_ * F_);
  const int*   esG = GE + (size_t)g * (2 * E_);

  // ---------------- CSR build ----------------
  if (tid < 256) fill[tid] = 0;
  __syncthreads();
  int s0 = esG[tid * 2], d0 = esG[E_ + tid * 2];
  int s1 = esG[tid * 2 + 1], d1 = esG[E_ + tid * 2 + 1];
  atomicAdd(&fill[d0], 1);
  atomicAdd(&fill[d1], 1);
  __syncthreads();
  int myrow = 0;
  if (tid < 256) {
    int deg = fill[tid];
    dinv_s[tid] = rsqrtf((float)deg + 1.f);
    int v = deg;
#pragma unroll
    for (int off = 1; off < 64; off <<= 1) {
      int u = __shfl_up(v, off);
      if (lane >= off) v += u;
    }
    if (lane == 63) ((int*)red)[w] = v;
    myrow = v - deg;
  }
  __syncthreads();
  if (tid < 256) {
    int pre = 0;
#pragma unroll
    for (int q = 0; q < 4; ++q) if (q < w) pre += ((int*)red)[q];
    rowst[tid] = myrow + pre;
    fill[tid] = 0;
  }
  __syncthreads();
  {
    int pos = rowst[d0] + atomicAdd(&fill[d0], 1);
    esrc[pos] = (unsigned short)s0;
    enorm[pos] = dinv_s[s0] * dinv_s[d0];
    pos = rowst[d1] + atomicAdd(&fill[d1], 1);
    esrc[pos] = (unsigned short)s1;
    enorm[pos] = dinv_s[s1] * dinv_s[d1];
  }
  __syncthreads();

  const int nd = tid >> 1, jhalf = tid & 1;
  const int rb = rowst[nd], rc = fill[nd];
  const float dii = dinv_s[nd] * dinv_s[nd];

  // ---------------- load X A-fragments ----------------
  short8 xA[2][4];
#pragma unroll
  for (int mt = 0; mt < 2; ++mt) {
    const float* xr = xg + (w * 32 + mt * 16 + l15) * F_ + l4 * 8;
#pragma unroll
    for (int ks = 0; ks < 4; ++ks) {
      float4 u = *(const float4*)(xr + ks * 32);
      float4 v2 = *(const float4*)(xr + ks * 32 + 4);
      short8 t;
      t[0] = (short)f2bf(u.x);  t[1] = (short)f2bf(u.y);
      t[2] = (short)f2bf(u.z);  t[3] = (short)f2bf(u.w);
      t[4] = (short)f2bf(v2.x); t[5] = (short)f2bf(v2.y);
      t[6] = (short)f2bf(v2.z); t[7] = (short)f2bf(v2.w);
      xA[mt][ks] = t;
    }
  }

  f32x4 acc2[2][4];
#pragma unroll
  for (int mt = 0; mt < 2; ++mt)
#pragma unroll
    for (int nt = 0; nt < 4; ++nt) acc2[mt][nt] = (f32x4){0.f, 0.f, 0.f, 0.f};

  // ---------------- fused conv1 (MFMA) + gather + relu + conv2 (MFMA), 4 chunks ----------------
  for (int c = 0; c < 4; ++c) {
    __syncthreads();
    f32x4 acc1[2][2];
#pragma unroll
    for (int mt = 0; mt < 2; ++mt) { acc1[mt][0] = (f32x4){0.f,0.f,0.f,0.f}; acc1[mt][1] = (f32x4){0.f,0.f,0.f,0.f}; }
#pragma unroll
    for (int ks = 0; ks < 4; ++ks) {
      short8 bA = *(const short8*)(W1F + (((2 * c + 0) * 4 + ks) * 64 + lane) * 8);
      short8 bB = *(const short8*)(W1F + (((2 * c + 1) * 4 + ks) * 64 + lane) * 8);
#pragma unroll
      for (int mt = 0; mt < 2; ++mt) {
        acc1[mt][0] = __builtin_amdgcn_mfma_f32_16x16x32_bf16(xA[mt][ks], bA, acc1[mt][0], 0, 0, 0);
        acc1[mt][1] = __builtin_amdgcn_mfma_f32_16x16x32_bf16(xA[mt][ks], bB, acc1[mt][1], 0, 0, 0);
      }
    }
#pragma unroll
    for (int mt = 0; mt < 2; ++mt)
#pragma unroll
      for (int ntl = 0; ntl < 2; ++ntl)
#pragma unroll
        for (int r = 0; r < 4; ++r)
          chunkA[(w * 32 + mt * 16 + l4 * 4 + r) * 40 + ntl * 16 + l15] = f2bf(acc1[mt][ntl][r]);
    __syncthreads();
    float gacc[16];
    {
      const unsigned short* rp = chunkA + nd * 40 + jhalf * 16;
      short8 v0 = *(const short8*)(rp);
      short8 v1 = *(const short8*)(rp + 8);
#pragma unroll
      for (int j = 0; j < 8; ++j) {
        gacc[j]     = dii * bf2f((unsigned short)v0[j]);
        gacc[8 + j] = dii * bf2f((unsigned short)v1[j]);
      }
    }
    for (int e = 0; e < rc; ++e) {
      int s = esrc[rb + e]; float nm = enorm[rb + e];
      const unsigned short* sp = chunkA + s * 40 + jhalf * 16;
      short8 v0 = *(const short8*)(sp);
      short8 v1 = *(const short8*)(sp + 8);
#pragma unroll
      for (int j = 0; j < 8; ++j) {
        gacc[j]     = fmaf(nm, bf2f((unsigned short)v0[j]), gacc[j]);
        gacc[8 + j] = fmaf(nm, bf2f((unsigned short)v1[j]), gacc[8 + j]);
      }
    }
    const float* bp = b1 + c * 32 + jhalf * 16;
    __syncthreads();
    {
      short8 o0, o1;
#pragma unroll
      for (int j = 0; j < 8; ++j) {
        o0[j] = (short)f2bf(fmaxf(gacc[j] + bp[j], 0.f));
        o1[j] = (short)f2bf(fmaxf(gacc[8 + j] + bp[8 + j], 0.f));
      }
      *(short8*)(chunkA + nd * 40 + jhalf * 16) = o0;
      *(short8*)(chunkA + nd * 40 + jhalf * 16 + 8) = o1;
    }
    __syncthreads();
    {
      short8 hA0 = *(const short8*)(chunkA + (w * 32 + 0 * 16 + l15) * 40 + l4 * 8);
      short8 hA1 = *(const short8*)(chunkA + (w * 32 + 1 * 16 + l15) * 40 + l4 * 8);
#pragma unroll
      for (int nt = 0; nt < 4; ++nt) {
        short8 bf = *(const short8*)(W2F + ((nt * 4 + c) * 64 + lane) * 8);
        acc2[0][nt] = __builtin_amdgcn_mfma_f32_16x16x32_bf16(hA0, bf, acc2[0][nt], 0, 0, 0);
        acc2[1][nt] = __builtin_amdgcn_mfma_f32_16x16x32_bf16(hA1, bf, acc2[1][nt], 0, 0, 0);
      }
    }
  }

  // ---------------- conv2 aggregation: xw2 -> h2s, gather, final h2 -> h2s + h2T ----------------
#pragma unroll
  for (int mt = 0; mt < 2; ++mt)
#pragma unroll
    for (int nt = 0; nt < 4; ++nt)
#pragma unroll
      for (int r = 0; r < 4; ++r)
        h2s[(w * 32 + mt * 16 + l4 * 4 + r) * 72 + nt * 16 + l15] = f2bf(acc2[mt][nt][r]);
  __syncthreads();
  float g2[32];
  {
    const unsigned short* rp = h2s + nd * 72 + jhalf * 32;
#pragma unroll
    for (int q = 0; q < 4; ++q) {
      short8 v = *(const short8*)(rp + q * 8);
#pragma unroll
      for (int j = 0; j < 8; ++j) g2[q * 8 + j] = dii * bf2f((unsigned short)v[j]);
    }
  }
  for (int e = 0; e < rc; ++e) {
    int s = esrc[rb + e]; float nm = enorm[rb + e];
    const unsigned short* sp = h2s + s * 72 + jhalf * 32;
#pragma unroll
    for (int q = 0; q < 4; ++q) {
      short8 v = *(const short8*)(sp + q * 8);
#pragma unroll
      for (int j = 0; j < 8; ++j) g2[q * 8 + j] = fmaf(nm, bf2f((unsigned short)v[j]), g2[q * 8 + j]);
    }
  }
  const float* b2p = b2 + jhalf * 32;
  __syncthreads();   // all xw2 reads done; chunkA fully dead -> h2T writable
  {
#pragma unroll
    for (int q = 0; q < 4; ++q) {
      short8 o;
#pragma unroll
      for (int j = 0; j < 8; ++j) o[j] = (short)f2bf(g2[q * 8 + j] + b2p[q * 8 + j]);
      *(short8*)(h2s + nd * 72 + jhalf * 32 + q * 8) = o;
    }
#pragma unroll
    for (int i = 0; i < 32; ++i)
      h2T[(jhalf * 32 + i) * 264 + nd] = f2bf(g2[i] + b2p[i]);
  }
  __syncthreads();

  // ---------------- attention: a = tanh(h2 @ Wf1 + bf1) via MFMA (Wf1 hi+lo) ----------------
  short8 hA[2][2];
#pragma unroll
  for (int mt = 0; mt < 2; ++mt)
#pragma unroll
    for (int ks = 0; ks < 2; ++ks)
      hA[mt][ks] = *(const short8*)(h2s + (w * 32 + mt * 16 + l15) * 72 + ks * 32 + l4 * 8);
  f32x4 aacc[2][2];
#pragma unroll
  for (int mt = 0; mt < 2; ++mt) { aacc[mt][0] = (f32x4){0.f,0.f,0.f,0.f}; aacc[mt][1] = (f32x4){0.f,0.f,0.f,0.f}; }
#pragma unroll
  for (int ks = 0; ks < 2; ++ks)
#pragma unroll
    for (int nt = 0; nt < 2; ++nt) {
      short8 bh = *(const short8*)(Wf1H + ((nt * 2 + ks) * 64 + lane) * 8);
      short8 bl = *(const short8*)(Wf1L + ((nt * 2 + ks) * 64 + lane) * 8);
#pragma unroll
      for (int mt = 0; mt < 2; ++mt) {
        aacc[mt][nt] = __builtin_amdgcn_mfma_f32_16x16x32_bf16(hA[mt][ks], bh, aacc[mt][nt], 0, 0, 0);
        aacc[mt][nt] = __builtin_amdgcn_mfma_f32_16x16x32_bf16(hA[mt][ks], bl, aacc[mt][nt], 0, 0, 0);
      }
    }
  __syncthreads();   // h2s A-frag reads done -> a_stf overlay writable
#pragma unroll
  for (int mt = 0; mt < 2; ++mt)
#pragma unroll
    for (int nt = 0; nt < 2; ++nt)
#pragma unroll
      for (int r = 0; r < 4; ++r)
        a_stf[(w * 32 + mt * 16 + l4 * 4 + r) * 34 + nt * 16 + l15] =
            tanhf(aacc[mt][nt][r] + bf1[nt * 16 + l15]);
  __syncthreads();

  // ---------------- l = a @ Wf2 + bf2 (fp32, per-thread); softmax over nodes ----------------
  float lv[8], ex[8];
  if (tid < 256) {
#pragma unroll
    for (int jj = 0; jj < 8; ++jj) lv[jj] = bf2[jj];
    const float* ar = a_stf + tid * 34;
    for (int j = 0; j < 32; ++j) {
      float av = ar[j];
      const float* wr = Wf2 + j * K2_;
#pragma unroll
      for (int jj = 0; jj < 8; ++jj) lv[jj] = fmaf(av, wr[jj], lv[jj]);
    }
    float mx[8];
#pragma unroll
    for (int jj = 0; jj < 8; ++jj) mx[jj] = lv[jj];
#pragma unroll
    for (int off = 1; off < 64; off <<= 1)
#pragma unroll
      for (int jj = 0; jj < 8; ++jj) mx[jj] = fmaxf(mx[jj], __shfl_xor(mx[jj], off));
    if (lane == 0)
#pragma unroll
      for (int jj = 0; jj < 8; ++jj) red[w * 8 + jj] = mx[jj];
  }
  __syncthreads();
  if (tid < 256) {
#pragma unroll
    for (int jj = 0; jj < 8; ++jj) {
      float m = fmaxf(fmaxf(red[jj], red[8 + jj]), fmaxf(red[16 + jj], red[24 + jj]));
      ex[jj] = expf(lv[jj] - m);
    }
    float sm[8];
#pragma unroll
    for (int jj = 0; jj < 8; ++jj) sm[jj] = ex[jj];
#pragma unroll
    for (int off = 1; off < 64; off <<= 1)
#pragma unroll
      for (int jj = 0; jj < 8; ++jj) sm[jj] += __shfl_xor(sm[jj], off);
    if (lane == 0)
#pragma unroll
      for (int jj = 0; jj < 8; ++jj) red[32 + w * 8 + jj] = sm[jj];
  }
  __syncthreads();
  if (tid < 256) {
#pragma unroll
    for (int jj = 0; jj < 8; ++jj) {
      float tot = red[32 + jj] + red[40 + jj] + red[48 + jj] + red[56 + jj];
      float av = ex[jj] / tot;
      unsigned short hi = f2bf(av);
      att_hi[jj * 264 + tid] = hi;
      att_lo[jj * 264 + tid] = f2bf(av - bf2f(hi));
    }
  }
  __syncthreads();

  // ---------------- emb (waves 0-3) + penalty (wave 4) via MFMA, att = hi+lo ----------------
  const int rl = l15 & 7;   // A rows 8-15 alias 0-7 (their D rows are discarded)
  if (w < 4) {
    f32x4 d = (f32x4){0.f, 0.f, 0.f, 0.f};
#pragma unroll
    for (int ks = 0; ks < 8; ++ks) {
      short8 ah = *(const short8*)(att_hi + rl * 264 + ks * 32 + l4 * 8);
      short8 al = *(const short8*)(att_lo + rl * 264 + ks * 32 + l4 * 8);
      short8 bv = *(const short8*)(h2T + (w * 16 + l15) * 264 + ks * 32 + l4 * 8);
      d = __builtin_amdgcn_mfma_f32_16x16x32_bf16(ah, bv, d, 0, 0, 0);
      d = __builtin_amdgcn_mfma_f32_16x16x32_bf16(al, bv, d, 0, 0, 0);
    }
    if (l4 < 2) {
      float* eg = ws + OFS_EMB + (size_t)g * 512;
#pragma unroll
      for (int r = 0; r < 4; ++r)
        eg[(l4 * 4 + r) * 64 + w * 16 + l15] = d[r];
    }
  } else if (w == 4) {
    f32x4 p = (f32x4){0.f, 0.f, 0.f, 0.f};
#pragma unroll
    for (int ks = 0; ks < 8; ++ks) {
      short8 ah = *(const short8*)(att_hi + rl * 264 + ks * 32 + l4 * 8);
      short8 al = *(const short8*)(att_lo + rl * 264 + ks * 32 + l4 * 8);
      p = __builtin_amdgcn_mfma_f32_16x16x32_bf16(ah, ah, p, 0, 0, 0);
      p = __builtin_amdgcn_mfma_f32_16x16x32_bf16(ah, al, p, 0, 0, 0);
      p = __builtin_amdgcn_mfma_f32_16x16x32_bf16(al, ah, p, 0, 0, 0);
    }
    if (l4 < 2 && l15 < 8) {
#pragma unroll
      for (int r = 0; r < 4; ++r) {
        float v = p[r];
        if (l4 * 4 + r == l15) v -= 1.f;
        red[64 + (l4 * 4 + r) * 8 + l15] = v * v;
      }
    }
  }
  __syncthreads();
  if (tid < 8) {
    float s2 = 0.f;
#pragma unroll
    for (int k = 0; k < 8; ++k) s2 += red[64 + tid * 8 + k];
    red[128 + tid] = sqrtf(s2);
  }
  __syncthreads();
  if (tid == 0) {
    float p = 0.f;
#pragma unroll
    for (int k = 0; k < 8; ++k) p += red[128 + k];
    atomicAdd(&ws[OFS_PEN], p);
  }
}

// ---------------- macro level ----------------
__global__ __launch_bounds__(1024)
void macro_csr(const int* __restrict__ me, float* __restrict__ ws) {
  __shared__ int cnt[1000];
  __shared__ float dinvL[1000];
  __shared__ int wtot[16];
  int t = threadIdx.x, lane = t & 63, wv = t >> 6;
  for (int i = t; i < 1000; i += 1024) cnt[i] = 0;
  __syncthreads();
  for (int e = t; e < ME_; e += 1024) atomicAdd(&cnt[me[ME_ + e]], 1);
  __syncthreads();
  int v = (t < 1000) ? cnt[t] : 0;
  float di = rsqrtf((float)v + 1.f);
  if (t < 1000) { dinvL[t] = di; ws[OFS_DINVM + t] = di; }
  int sc = v;
#pragma unroll
  for (int off = 1; off < 64; off <<= 1) {
    int u = __shfl_up(sc, off);
    if (lane >= off) sc += u;
  }
  if (lane == 63) wtot[wv] = sc;
  __syncthreads();
  int pre = 0;
#pragma unroll
  for (int q = 0; q < 16; ++q) if (q < wv) pre += wtot[q];
  int rs = pre + sc - v;   // exclusive prefix
  int* rowstM = (int*)(ws + OFS_ROWSTM);
  if (t < 1000) rowstM[t] = rs;
  if (t == 0) rowstM[1000] = ME_;
  __syncthreads();
  if (t < 1000) cnt[t] = rs;
  __syncthreads();
  unsigned short* wsrc = (unsigned short*)(ws + OFS_WSRC);
  for (int e = t; e < ME_; e += 1024) {
    int s = me[e], d = me[ME_ + e];
    int pos = atomicAdd(&cnt[d], 1);
    wsrc[pos] = (unsigned short)s;
    ws[OFS_WNORM + pos] = dinvL[s] * dinvL[d];
  }
}

__global__ __launch_bounds__(128)
void macro1(const float* __restrict__ Wm1, float* __restrict__ ws) {
  __shared__ float er[512];
  int g = blockIdx.x, t = threadIdx.x;
  *(float4*)&er[t * 4] = *(const float4*)&ws[OFS_EMB + (size_t)g * 512 + t * 4];
  __syncthreads();
  float acc = 0.f;
#pragma unroll 4
  for (int k = 0; k < 512; ++k) acc = fmaf(er[k], Wm1[k * MD_ + t], acc);
  ws[OFS_XW1M + g * MD_ + t] = acc;
}

__global__ __launch_bounds__(128)
void macro2(const float* __restrict__ bm1, const float* __restrict__ Wm2, float* __restrict__ ws) {
  __shared__ float wred[2][10];
  int g = blockIdx.x, t = threadIdx.x;
  const int* rowstM = (const int*)(ws + OFS_ROWSTM);
  const unsigned short* wsrc = (const unsigned short*)(ws + OFS_WSRC);
  int e0 = rowstM[g], e1 = rowstM[g + 1];
  float di = ws[OFS_DINVM + g];
  float acc = di * di * ws[OFS_XW1M + g * MD_ + t];
  for (int e = e0; e < e1; ++e)
    acc = fmaf(ws[OFS_WNORM + e], ws[OFS_XW1M + (int)wsrc[e] * MD_ + t], acc);
  float hv = fmaxf(acc + bm1[t], 0.f);
  float part[10];
#pragma unroll
  for (int j = 0; j < 10; ++j) part[j] = hv * Wm2[t * LB_ + j];
#pragma unroll
  for (int off = 1; off < 64; off <<= 1)
#pragma unroll
    for (int j = 0; j < 10; ++j) part[j] += __shfl_xor(part[j], off);
  if ((t & 63) == 0)
#pragma unroll
    for (int j = 0; j < 10; ++j) wred[t >> 6][j] = part[j];
  __syncthreads();
  if (t < 10) ws[OFS_XW2M + g * LB_ + t] = wred[0][t] + wred[1][t];
}

__global__ __launch_bounds__(64)
void macro3(const float* __restrict__ bm2, const float* __restrict__ ws, float* __restrict__ out) {
  int g = blockIdx.x, t = threadIdx.x;
  const int* rowstM = (const int*)(ws + OFS_ROWSTM);
  const unsigned short* wsrc = (const unsigned short*)(ws + OFS_WSRC);
  int e0 = rowstM[g], e1 = rowstM[g + 1];
  float di = ws[OFS_DINVM + g];
  float lg = -1e30f;
  if (t < 10) {
    float acc = di * di * ws[OFS_XW2M + g * LB_ + t];
    for (int e = e0; e < e1; ++e)
      acc = fmaf(ws[OFS_WNORM + e], ws[OFS_XW2M + (int)wsrc[e] * LB_ + t], acc);
    lg = acc + bm2[t];
  }
  float m = lg;
#pragma unroll
  for (int off = 1; off < 16; off <<= 1) m = fmaxf(m, __shfl_xor(m, off));
  float e_ = (t < 10) ? expf(lg - m) : 0.f;
  float s = e_;
#pragma unroll
  for (int off = 1; off < 16; off <<= 1) s += __shfl_xor(s, off);
  if (t < 10) out[g * LB_ + t] = lg - m - logf(s);
  if (g == 0 && t == 63) out[10000] = ws[OFS_PEN] * 0.001f;
}

extern "C" void kernel_launch(void* const* d_in, const int* in_sizes, int n_in,
                              void* d_out, int out_size, void* d_ws, size_t ws_size,
                              hipStream_t stream)
{
  const float* X   = (const float*)d_in[0];
  const int*   GE  = (const int*)d_in[1];
  const int*   MEe = (const int*)d_in[2];
  const float* W1  = (const float*)d_in[3];
  const float* b1  = (const float*)d_in[4];
  const float* W2  = (const float*)d_in[5];
  const float* b2  = (const float*)d_in[6];
  const float* Wf1 = (const float*)d_in[7];
  const float* bf1 = (const float*)d_in[8];
  const float* Wf2 = (const float*)d_in[9];
  const float* bf2 = (const float*)d_in[10];
  const float* Wm1 = (const float*)d_in[11];
  const float* bm1 = (const float*)d_in[12];
  const float* Wm2 = (const float*)d_in[13];
  const float* bm2 = (const float*)d_in[14];
  float* ws  = (float*)d_ws;
  float* out = (float*)d_out;

  unsigned short* frag = (unsigned short*)(ws + OFS_WFRAG);

  prep_kernel<<<32, 256, 0, stream>>>(W1, W2, Wf1, frag, ws);
  macro_csr<<<1, 1024, 0, stream>>>(MEe, ws);

  size_t lds = 80896;
  graph_kernel<<<G_, 512, lds, stream>>>(X, GE, frag, b1, b2, bf1, bf2, Wf2, ws);

  macro1<<<G_, 128, 0, stream>>>(Wm1, ws);
  macro2<<<G_, 128, 0, stream>>>(bm1, Wm2, ws);
  macro3<<<G_, 64, 0, stream>>>(bm2, ws, out);
}